// Round 1
// baseline (81.926 us; speedup 1.0000x reference)
//
#include <hip/hip_runtime.h>
#include <hip/hip_bf16.h>

// NT-Xent loss, MI355X. B=4096, D=256, N=8192, temp=0.5.
// Plan: normalize -> bf16 zn in ws -> MFMA Gram tiles with fused exp/LSE
// partials (j split 8-way for parallelism) -> tiny finalize.

typedef __attribute__((ext_vector_type(4))) float f32x4;
typedef __attribute__((ext_vector_type(8))) short s16x8;

#define N_TOT 8192
#define B_HALF 4096
#define D_DIM 256
#define INV_T 2.0f
#define JSPLIT 8

__device__ inline unsigned short f2bf(float f) {
  __hip_bfloat16 h = __float2bfloat16(f);
  return *reinterpret_cast<unsigned short*>(&h);
}

// One wave per row: sumsq reduce, scale, write bf16.
__global__ __launch_bounds__(256) void nrm_kernel(const float* __restrict__ z1,
                                                  const float* __restrict__ z2,
                                                  unsigned short* __restrict__ zn) {
  int row = blockIdx.x * 4 + (threadIdx.x >> 6);
  int lane = threadIdx.x & 63;
  const float* src = (row < B_HALF) ? (z1 + (size_t)row * D_DIM)
                                    : (z2 + (size_t)(row - B_HALF) * D_DIM);
  f32x4 v = *reinterpret_cast<const f32x4*>(src + lane * 4);
  float ss = v.x * v.x + v.y * v.y + v.z * v.z + v.w * v.w;
#pragma unroll
  for (int m = 32; m >= 1; m >>= 1) ss += __shfl_xor(ss, m);
  float inv = 1.0f / fmaxf(sqrtf(ss), 1e-8f);
  ushort4 o;
  o.x = f2bf(v.x * inv);
  o.y = f2bf(v.y * inv);
  o.z = f2bf(v.z * inv);
  o.w = f2bf(v.w * inv);
  *reinterpret_cast<ushort4*>(zn + (size_t)row * D_DIM + lane * 4) = o;
}

// Block: 64 sim-rows x 1024 sim-cols (j-split blockIdx.y of 8).
// 4 waves, each wave 16 rows. A frags in registers, B tiles staged in LDS
// (64x256 bf16, 32KB) with XOR swizzle to keep ds_read_b128 bank-uniform.
__global__ __launch_bounds__(256) void gram_kernel(const unsigned short* __restrict__ zn,
                                                   float* __restrict__ psum,
                                                   float* __restrict__ ppos) {
  __shared__ __align__(16) char bt[64 * 512];
  const int tid = threadIdx.x;
  const int w = tid >> 6, l = tid & 63;
  const int lm = l & 15, hh = l >> 4;
  const int r0 = blockIdx.x * 64 + w * 16;
  const int js = blockIdx.y;
  const char* znb = reinterpret_cast<const char*>(zn);

  // A fragments: lane holds row (r0+lm), k = g*32 + hh*8 .. +7 (8 bf16 = 16B)
  s16x8 a[8];
#pragma unroll
  for (int g = 0; g < 8; ++g)
    a[g] = *reinterpret_cast<const s16x8*>(znb + (size_t)(r0 + lm) * 512 + g * 64 + hh * 16);

  float sumexp[4] = {0.f, 0.f, 0.f, 0.f};
  float pos[4] = {0.f, 0.f, 0.f, 0.f};
  const int swz = (l & 7) << 4;  // == (brow&7)<<4 since brow = jt*16 + lm

  for (int stp = 0; stp < 16; ++stp) {
    const int jrow = js * 1024 + stp * 64;
    // stage 64 B-rows; coalesced global reads, swizzled LDS writes
#pragma unroll
    for (int k = 0; k < 8; ++k) {
      int ci = tid + k * 256;
      int r = ci >> 5, c = ci & 31;
      s16x8 val = *reinterpret_cast<const s16x8*>(znb + (size_t)(jrow + r) * 512 + c * 16);
      *reinterpret_cast<s16x8*>(bt + r * 512 + ((c * 16) ^ ((r & 7) << 4))) = val;
    }
    __syncthreads();
#pragma unroll
    for (int jt = 0; jt < 4; ++jt) {
      f32x4 acc = {0.f, 0.f, 0.f, 0.f};
      const char* bp = bt + (jt * 16 + lm) * 512;
#pragma unroll
      for (int g = 0; g < 8; ++g) {
        s16x8 b = *reinterpret_cast<const s16x8*>(bp + ((g * 64 + hh * 16) ^ swz));
        acc = __builtin_amdgcn_mfma_f32_16x16x32_bf16(a[g], b, acc, 0, 0, 0);
      }
      const int j = jrow + jt * 16 + lm;
#pragma unroll
      for (int t = 0; t < 4; ++t) {
        const int i = r0 + hh * 4 + t;  // verified C/D map: row=(l>>4)*4+t, col=l&15
        float s = acc[t] * INV_T;
        float sm = (j == i) ? -1e30f : s;  // diagonal mask -> exp = 0
        sumexp[t] += __expf(sm);
        if (j == (i ^ B_HALF)) pos[t] += s;  // positive pair: (i+B) mod 2B == i^B
      }
    }
    __syncthreads();
  }

  // reduce across the 16 lanes sharing each row (col dimension of D)
#pragma unroll
  for (int t = 0; t < 4; ++t) {
#pragma unroll
    for (int m = 1; m < 16; m <<= 1) {
      sumexp[t] += __shfl_xor(sumexp[t], m);
      pos[t] += __shfl_xor(pos[t], m);
    }
  }
  if (lm == 0) {
#pragma unroll
    for (int t = 0; t < 4; ++t) {
      int i = r0 + hh * 4 + t;
      psum[js * N_TOT + i] = sumexp[t];
      ppos[js * N_TOT + i] = pos[t];
    }
  }
}

__global__ __launch_bounds__(256) void fin_kernel(const float* __restrict__ psum,
                                                  const float* __restrict__ ppos,
                                                  float* __restrict__ out) {
  float acc = 0.f;
  for (int i = threadIdx.x; i < N_TOT; i += 256) {
    float se = 0.f, p = 0.f;
#pragma unroll
    for (int s = 0; s < JSPLIT; ++s) {
      se += psum[s * N_TOT + i];
      p += ppos[s * N_TOT + i];
    }
    acc += logf(se) - p;
  }
#pragma unroll
  for (int m = 32; m >= 1; m >>= 1) acc += __shfl_xor(acc, m);
  __shared__ float red[4];
  if ((threadIdx.x & 63) == 0) red[threadIdx.x >> 6] = acc;
  __syncthreads();
  if (threadIdx.x == 0) out[0] = (red[0] + red[1] + red[2] + red[3]) / (float)N_TOT;
}

extern "C" void kernel_launch(void* const* d_in, const int* in_sizes, int n_in,
                              void* d_out, int out_size, void* d_ws, size_t ws_size,
                              hipStream_t stream) {
  const float* z1 = (const float*)d_in[0];
  const float* z2 = (const float*)d_in[1];
  float* out = (float*)d_out;
  char* ws = (char*)d_ws;

  unsigned short* zn = (unsigned short*)ws;              // 8192*256*2 = 4 MiB
  float* psum = (float*)(ws + (size_t)N_TOT * D_DIM * 2);  // 8*8192 f32
  float* ppos = psum + JSPLIT * N_TOT;                     // 8*8192 f32

  nrm_kernel<<<N_TOT / 4, 256, 0, stream>>>(z1, z2, zn);
  gram_kernel<<<dim3(N_TOT / 64, JSPLIT), 256, 0, stream>>>(zn, psum, ppos);
  fin_kernel<<<1, 256, 0, stream>>>(psum, ppos, out);
}